// Round 20
// baseline (575.832 us; speedup 1.0000x reference)
//
#include <hip/hip_runtime.h>
#include <hip/hip_bf16.h>

#define BB 8
#define NN 2048
#define KK 20
#define KSEL 32
#define SCAP 256

typedef __attribute__((ext_vector_type(8))) short short8v;   // 8 bf16 (4 VGPR)
typedef __attribute__((ext_vector_type(4))) float f32x4;

// ============ per-point squared norms (fp64 acc, fp32 out) ============
__global__ __launch_bounds__(256) void norms_k(const float* __restrict__ xin, int C, int stride,
                                               float* __restrict__ xx) {
  int p = blockIdx.x * 256 + threadIdx.x;
  if (p >= BB * NN) return;
  const float* r = xin + (size_t)p * stride;
  double s = 0.0;
  for (int c = 0; c < C; ++c) { double v = (double)r[c]; s += v * v; }
  xx[p] = (float)s;
}

// ============ fallback: full ballot bit-search (verified semantics) ============
__device__ __forceinline__ void bitsel_fallback(unsigned (&u)[32], int lane,
                                                int* __restrict__ outp)
{
  unsigned long long lmask = (1ull << lane) - 1ull;
  unsigned T = 0;
  bool exact = false;
  for (int b = 31; b >= 0; --b) {
    unsigned Tp = T | (1u << b);
    int cnt = 0;
#pragma unroll
    for (int q = 0; q < 32; ++q)
      cnt += __popcll(__ballot(u[q] >= Tp));
    if (cnt >= KSEL) {
      T = Tp;
      if (cnt == KSEL) { exact = true; break; }
    }
  }
  int cnt = 0;
#pragma unroll
  for (int q = 0; q < 32; ++q) {
    bool take = exact ? (u[q] >= T) : (u[q] > T);
    unsigned long long m = __ballot(take);
    if (take) outp[cnt + __popcll(m & lmask)] = lane + 64 * q;
    cnt += __popcll(m);
  }
  if (!exact) {
    int tneed = KSEL - cnt;
#pragma unroll
    for (int q = 0; q < 32; ++q) {
      if (tneed > 0) {
        bool eq = (u[q] == T);
        unsigned long long m = __ballot(eq);
        int before = __popcll(m & lmask);
        if (eq && before < tneed) outp[cnt + before] = lane + 64 * q;
        int c = __popcll(m);
        int used = c < tneed ? c : tneed;
        cnt += used; tneed -= used;
      }
    }
  }
}

// ============ threshold+compaction top-KSEL select (wave-local, no atomics) ============
__device__ __forceinline__ void thresel32(unsigned (&u)[32], int lane,
                                          unsigned* __restrict__ cv, int* __restrict__ ci,
                                          int* __restrict__ outp)
{
  unsigned long long lmask = (1ull << lane) - 1ull;
  unsigned lm = u[0];
#pragma unroll
  for (int q = 1; q < 32; ++q) lm = u[q] > lm ? u[q] : lm;
  unsigned T = 0;
  for (int b = 31; b >= 0; --b) {
    unsigned Tp = T | (1u << b);
    int c = __popcll(__ballot(lm >= Tp));
    if (c >= 32) { T = Tp; if (c == 32) break; }
  }
  int n0 = 0;
#pragma unroll
  for (int q = 0; q < 32; ++q) n0 += __popcll(__ballot(u[q] >= T));
  if (n0 <= SCAP) {
    int cnt = 0;
#pragma unroll
    for (int q = 0; q < 32; ++q) {
      bool take = u[q] >= T;
      unsigned long long m = __ballot(take);
      if (take) {
        int pos = cnt + __popcll(m & lmask);
        cv[pos] = u[q];
        ci[pos] = lane + 64 * q;
      }
      cnt += __popcll(m);
    }
    for (int i = lane; i < n0; i += 64) {
      unsigned vi = cv[i];
      int rank = 0;
      for (int j = 0; j < n0; ++j) {
        unsigned vj = cv[j];
        rank += (vj > vi || (vj == vi && j < i)) ? 1 : 0;
      }
      if (rank < KSEL) outp[rank] = ci[i];
    }
  } else {
    bitsel_fallback(u, lane, outp);
  }
}

// ============ layer-1 fused kNN (C=3): direct distances from LDS ============
__global__ __launch_bounds__(256) void knn3_k(const float* __restrict__ xin,
                                              int* __restrict__ cand)
{
  int t = threadIdx.x;
  int wv = t >> 6, lane = t & 63;
  const int BPB = NN / 16;
  int b = blockIdx.x / BPB;
  int p0 = (blockIdx.x % BPB) * 16;
  __shared__ float xs[3][NN];
  __shared__ unsigned cvs[4][SCAP];
  __shared__ int cis[4][SCAP];
  const float* xb = xin + (size_t)b * NN * 3;
  for (int e = t; e < NN * 3; e += 256) xs[e % 3][e / 3] = xb[e];
  __syncthreads();
  for (int rr = 0; rr < 4; ++rr) {
    int row = p0 + wv * 4 + rr;
    float xi0 = xs[0][row], xi1 = xs[1][row], xi2 = xs[2][row];
    unsigned u[32];
#pragma unroll
    for (int q = 0; q < 32; ++q) {
      int j = lane + 64 * q;
      float d0 = xi0 - xs[0][j], d1 = xi1 - xs[1][j], d2 = xi2 - xs[2][j];
      float v = -(d0 * d0 + d1 * d1 + d2 * d2);
      unsigned bb = __float_as_uint(v);
      u[q] = bb ^ (((unsigned)((int)bb >> 31)) | 0x80000000u);
    }
    thresel32(u, lane, cvs[wv], cis[wv], cand + ((size_t)(b * NN + row)) * KSEL);
  }
}

// ============ pd via split-bf16 MFMA (layers 2-4): D = 2*(hh+hl+lh) - xx_i - xx_j ============
// 512 threads / 8 waves, 128x128 tile, BK=64 (replay-verified round 18).
__global__ __launch_bounds__(512) void pdmfma_k(
    const unsigned short* __restrict__ Ah, const unsigned short* __restrict__ Al,
    int lda, long long az,
    float* __restrict__ D, const float* __restrict__ xx, int Kd)
{
  __shared__ unsigned short AsH[128 * 64];
  __shared__ unsigned short AsL[128 * 64];
  __shared__ unsigned short BsH[128 * 64];
  __shared__ unsigned short BsL[128 * 64];
  int z = blockIdx.z;
  const unsigned short* Ahb = Ah + az * z;
  const unsigned short* Alb = Al + az * z;
  float* Db = D + (size_t)NN * NN * z;
  const float* xxb = xx + (size_t)NN * z;
  int t = threadIdx.x;
  int w = t >> 6, lane = t & 63;
  int wm = w >> 2, wn = w & 3;
  int i0 = blockIdx.x * 128, j0 = blockIdx.y * 128;
  int fr = lane & 15, fg = lane >> 4;
  int srow = t >> 3;
  int scol = (t & 7) * 8;
  f32x4 acc[4][2] = {};
  for (int k0 = 0; k0 < Kd; k0 += 64) {
    short8v vah[2], valo[2], vbh[2], vbl[2];
#pragma unroll
    for (int rr = 0; rr < 2; ++rr) {
      int row = srow + rr * 64;
      vah[rr]  = *(const short8v*)(Ahb + (size_t)(i0 + row) * lda + k0 + scol);
      valo[rr] = *(const short8v*)(Alb + (size_t)(i0 + row) * lda + k0 + scol);
      vbh[rr]  = *(const short8v*)(Ahb + (size_t)(j0 + row) * lda + k0 + scol);
      vbl[rr]  = *(const short8v*)(Alb + (size_t)(j0 + row) * lda + k0 + scol);
    }
    __syncthreads();
#pragma unroll
    for (int rr = 0; rr < 2; ++rr) {
      int row = srow + rr * 64;
      int sw = (row * 64 + scol) ^ ((row & 7) << 3);
      *(short8v*)&AsH[sw] = vah[rr];
      *(short8v*)&AsL[sw] = valo[rr];
      *(short8v*)&BsH[sw] = vbh[rr];
      *(short8v*)&BsL[sw] = vbl[rr];
    }
    __syncthreads();
#pragma unroll
    for (int kk = 0; kk < 2; ++kk) {
      short8v ah[4], al[4], bh[2], bl[2];
      int kb = kk * 32 + fg * 8;
#pragma unroll
      for (int m = 0; m < 4; ++m) {
        int ar = wm * 64 + m * 16 + fr;
        int ai = (ar * 64 + kb) ^ ((ar & 7) << 3);
        ah[m] = *(const short8v*)&AsH[ai];
        al[m] = *(const short8v*)&AsL[ai];
      }
#pragma unroll
      for (int n = 0; n < 2; ++n) {
        int br = wn * 32 + n * 16 + fr;
        int bi = (br * 64 + kb) ^ ((br & 7) << 3);
        bh[n] = *(const short8v*)&BsH[bi];
        bl[n] = *(const short8v*)&BsL[bi];
      }
#pragma unroll
      for (int m = 0; m < 4; ++m)
#pragma unroll
        for (int n = 0; n < 2; ++n) {
          acc[m][n] = __builtin_amdgcn_mfma_f32_16x16x32_bf16(ah[m], bh[n], acc[m][n], 0, 0, 0);
          acc[m][n] = __builtin_amdgcn_mfma_f32_16x16x32_bf16(ah[m], bl[n], acc[m][n], 0, 0, 0);
          acc[m][n] = __builtin_amdgcn_mfma_f32_16x16x32_bf16(al[m], bh[n], acc[m][n], 0, 0, 0);
        }
    }
    __syncthreads();
  }
#pragma unroll
  for (int m = 0; m < 4; ++m) {
    float xi[4];
#pragma unroll
    for (int j = 0; j < 4; ++j) xi[j] = xxb[i0 + wm * 64 + m * 16 + fg * 4 + j];
#pragma unroll
    for (int n = 0; n < 2; ++n) {
      float xj = xxb[j0 + wn * 32 + n * 16 + fr];
#pragma unroll
      for (int j = 0; j < 4; ++j)
        Db[(size_t)(i0 + wm * 64 + m * 16 + fg * 4 + j) * NN +
           j0 + wn * 32 + n * 16 + fr] = 2.f * acc[m][n][j] - xi[j] - xj;
    }
  }
}

// ============ feature GEMM via split-bf16 MFMA (layers 2-4): Z = X * Wmod^T ============
__global__ __launch_bounds__(512) void gemm_fb_k(
    const unsigned short* __restrict__ Ah, const unsigned short* __restrict__ Al, int lda,
    const unsigned short* __restrict__ Bh, const unsigned short* __restrict__ Bl, int ldb,
    float* __restrict__ C, int ldc, int Kd)
{
  __shared__ unsigned short AsH[128 * 64];
  __shared__ unsigned short AsL[128 * 64];
  __shared__ unsigned short BsH[128 * 64];
  __shared__ unsigned short BsL[128 * 64];
  int t = threadIdx.x;
  int w = t >> 6, lane = t & 63;
  int wm = w >> 2, wn = w & 3;
  int i0 = blockIdx.x * 128, j0 = blockIdx.y * 128;
  int fr = lane & 15, fg = lane >> 4;
  int srow = t >> 3;
  int scol = (t & 7) * 8;
  f32x4 acc[4][2] = {};
  for (int k0 = 0; k0 < Kd; k0 += 64) {
    short8v vah[2], valo[2], vbh[2], vbl[2];
#pragma unroll
    for (int rr = 0; rr < 2; ++rr) {
      int row = srow + rr * 64;
      vah[rr]  = *(const short8v*)(Ah + (size_t)(i0 + row) * lda + k0 + scol);
      valo[rr] = *(const short8v*)(Al + (size_t)(i0 + row) * lda + k0 + scol);
      vbh[rr]  = *(const short8v*)(Bh + (size_t)(j0 + row) * ldb + k0 + scol);
      vbl[rr]  = *(const short8v*)(Bl + (size_t)(j0 + row) * ldb + k0 + scol);
    }
    __syncthreads();
#pragma unroll
    for (int rr = 0; rr < 2; ++rr) {
      int row = srow + rr * 64;
      int sw = (row * 64 + scol) ^ ((row & 7) << 3);
      *(short8v*)&AsH[sw] = vah[rr];
      *(short8v*)&AsL[sw] = valo[rr];
      *(short8v*)&BsH[sw] = vbh[rr];
      *(short8v*)&BsL[sw] = vbl[rr];
    }
    __syncthreads();
#pragma unroll
    for (int kk = 0; kk < 2; ++kk) {
      short8v ah[4], al[4], bh[2], bl[2];
      int kb = kk * 32 + fg * 8;
#pragma unroll
      for (int m = 0; m < 4; ++m) {
        int ar = wm * 64 + m * 16 + fr;
        int ai = (ar * 64 + kb) ^ ((ar & 7) << 3);
        ah[m] = *(const short8v*)&AsH[ai];
        al[m] = *(const short8v*)&AsL[ai];
      }
#pragma unroll
      for (int n = 0; n < 2; ++n) {
        int br = wn * 32 + n * 16 + fr;
        int bi = (br * 64 + kb) ^ ((br & 7) << 3);
        bh[n] = *(const short8v*)&BsH[bi];
        bl[n] = *(const short8v*)&BsL[bi];
      }
#pragma unroll
      for (int m = 0; m < 4; ++m)
#pragma unroll
        for (int n = 0; n < 2; ++n) {
          acc[m][n] = __builtin_amdgcn_mfma_f32_16x16x32_bf16(ah[m], bh[n], acc[m][n], 0, 0, 0);
          acc[m][n] = __builtin_amdgcn_mfma_f32_16x16x32_bf16(ah[m], bl[n], acc[m][n], 0, 0, 0);
          acc[m][n] = __builtin_amdgcn_mfma_f32_16x16x32_bf16(al[m], bh[n], acc[m][n], 0, 0, 0);
        }
    }
    __syncthreads();
  }
#pragma unroll
  for (int m = 0; m < 4; ++m)
#pragma unroll
    for (int n = 0; n < 2; ++n)
#pragma unroll
      for (int j = 0; j < 4; ++j)
        C[(size_t)(i0 + wm * 64 + m * 16 + fg * 4 + j) * ldc +
          j0 + wn * 32 + n * 16 + fr] = acc[m][n][j];
}

// ============ top-KSEL candidates per row, one wave per row ============
__global__ __launch_bounds__(256) void topk32_k(const float* __restrict__ dist, int row0,
                                                int* __restrict__ cand)
{
  int wv = threadIdx.x >> 6;
  int row = blockIdx.x * 4 + wv;
  int lane = threadIdx.x & 63;
  const float* d = dist + (size_t)row * NN;
  unsigned u[32];
#pragma unroll
  for (int q = 0; q < 32; ++q) {
    unsigned b = __float_as_uint(d[lane + 64 * q]);
    unsigned mk = ((unsigned)((int)b >> 31)) | 0x80000000u;
    u[q] = b ^ mk;
  }
  __shared__ unsigned cvs[4][SCAP];
  __shared__ int cis[4][SCAP];
  thresel32(u, lane, cvs[wv], cis[wv], cand + (size_t)(row0 + row) * KSEL);
}

// ============ refine v4: templated C -> fully unrolled gather (max load ILP) ============
template <int C>
__global__ __launch_bounds__(256) void refine4_k(const float* __restrict__ xin, int stride,
                                                 const int* __restrict__ cand,
                                                 int* __restrict__ idxout)
{
  int t = threadIdx.x;
  int w = t >> 6, lane = t & 63;
  int p = blockIdx.x * 4 + w;
  int b = p >> 11;
  __shared__ float xi[4][C < 4 ? 4 : C];
  __shared__ double Lval[4][KSEL];
  __shared__ int Lidx[4][KSEL];
#pragma unroll
  for (int c = lane; c < C; c += 64) xi[w][c] = xin[(size_t)p * stride + c];
  __syncthreads();
  int m = lane >> 1, h = lane & 1;
  int q = cand[(size_t)p * KSEL + m];
  const float* xr = xin + (size_t)(b * NN + q) * stride;
  double s;
  if constexpr (C >= 8) {
    constexpr int half = C >> 1;
    int c0 = h * half;
    float4 v[half / 4];
#pragma unroll
    for (int i = 0; i < half / 4; ++i) v[i] = *(const float4*)(xr + c0 + 4 * i);
    double a0 = 0.0, a1 = 0.0, a2 = 0.0, a3 = 0.0;
#pragma unroll
    for (int i = 0; i < half / 4; ++i) {
      float4 xv = *(const float4*)(&xi[w][c0 + 4 * i]);
      double d0 = (double)xv.x - (double)v[i].x;
      double d1 = (double)xv.y - (double)v[i].y;
      double d2 = (double)xv.z - (double)v[i].z;
      double d3 = (double)xv.w - (double)v[i].w;
      a0 += d0 * d0; a1 += d1 * d1; a2 += d2 * d2; a3 += d3 * d3;
    }
    s = (a0 + a1) + (a2 + a3);
  } else {
    s = 0.0;
#pragma unroll
    for (int c = h; c < C; c += 2) {
      double d = (double)xi[w][c] - (double)xr[c];
      s += d * d;
    }
  }
  s += __shfl_xor(s, 1);
  if (h == 0) { Lval[w][m] = -s; Lidx[w][m] = q; }
  __syncthreads();
  int mm = lane & 31;
  double vm = Lval[w][mm];
  int im = Lidx[w][mm];
  int rank = 0;
#pragma unroll
  for (int j = 0; j < KSEL; ++j) {
    double vj = Lval[w][j];
    int ij = Lidx[w][j];
    rank += (vj > vm || (vj == vm && ij < im)) ? 1 : 0;
  }
  if (lane < 32 && rank < KK) idxout[(size_t)p * KK + rank] = im;
}

// ============ generic 128x128-tile fp32 GEMM: C = A * B^T (layer-1 feature GEMM) ============
__global__ __launch_bounds__(256) void gemm128_k(
    const float* __restrict__ A, int lda,
    const float* __restrict__ Bm, int ldb,
    float* __restrict__ C, int ldc, int Kd)
{
  __shared__ float As[128 * 68];
  __shared__ float Bs[128 * 68];
  int i0 = blockIdx.x * 128;
  int j0 = blockIdx.y * 128;
  int t = threadIdx.x;
  int tx = t & 15, ty = t >> 4;
  float acc[8][8] = {};
  for (int k0 = 0; k0 < Kd; k0 += 64) {
    int kt = Kd - k0; if (kt > 64) kt = 64;
    if (kt == 64) {
      for (int e = t; e < 128 * 64; e += 256) {
        int i = e >> 6, c = e & 63;
        As[i * 68 + c] = A[(size_t)(i0 + i) * lda + k0 + c];
        Bs[i * 68 + c] = Bm[(size_t)(j0 + i) * ldb + k0 + c];
      }
    } else {
      for (int e = t; e < 128 * kt; e += 256) {
        int i = e / kt, c = e % kt;
        As[i * 68 + c] = A[(size_t)(i0 + i) * lda + k0 + c];
        Bs[i * 68 + c] = Bm[(size_t)(j0 + i) * ldb + k0 + c];
      }
    }
    __syncthreads();
    int kt4 = kt & ~3;
    for (int c = 0; c < kt4; c += 4) {
      float4 a4[8], b4[8];
#pragma unroll
      for (int r = 0; r < 8; ++r) a4[r] = *(const float4*)&As[(ty + 16 * r) * 68 + c];
#pragma unroll
      for (int q = 0; q < 8; ++q) b4[q] = *(const float4*)&Bs[(tx + 16 * q) * 68 + c];
#pragma unroll
      for (int r = 0; r < 8; ++r)
#pragma unroll
        for (int q = 0; q < 8; ++q)
          acc[r][q] += a4[r].x * b4[q].x + a4[r].y * b4[q].y +
                       a4[r].z * b4[q].z + a4[r].w * b4[q].w;
    }
    for (int c = kt4; c < kt; ++c) {
      float av[8], bv[8];
#pragma unroll
      for (int r = 0; r < 8; ++r) av[r] = As[(ty + 16 * r) * 68 + c];
#pragma unroll
      for (int q = 0; q < 8; ++q) bv[q] = Bs[(tx + 16 * q) * 68 + c];
#pragma unroll
      for (int r = 0; r < 8; ++r)
#pragma unroll
        for (int q = 0; q < 8; ++q) acc[r][q] += av[r] * bv[q];
    }
    __syncthreads();
  }
#pragma unroll
  for (int r = 0; r < 8; ++r)
#pragma unroll
    for (int q = 0; q < 8; ++q)
      C[(size_t)(i0 + ty + 16 * r) * ldc + j0 + tx + 16 * q] = acc[r][q];
}

// ============ conv5 bf16 MFMA GEMM with FUSED stats epilogue (no C write) ============
__global__ __launch_bounds__(256) void gemm_c5_k(
    const unsigned short* __restrict__ A, int lda,
    const unsigned short* __restrict__ B, int ldb,
    float* __restrict__ pmx, float* __restrict__ pmn,
    double* __restrict__ psum, double* __restrict__ psq, int Kd)
{
  __shared__ unsigned short Asm[128 * 64];
  __shared__ unsigned short Bsm[128 * 64];
  int t = threadIdx.x;
  int w = t >> 6, lane = t & 63;
  int wm = w >> 1, wn = w & 1;
  int i0 = blockIdx.x * 128, j0 = blockIdx.y * 128;
  int fr = lane & 15, fg = lane >> 4;
  int srow = t >> 3;
  int scol = (t & 7) * 8;
  f32x4 acc[4][4] = {};
  for (int k0 = 0; k0 < Kd; k0 += 64) {
    short8v va[4], vb[4];
#pragma unroll
    for (int rr = 0; rr < 4; ++rr) {
      int row = srow + rr * 32;
      va[rr] = *(const short8v*)(A + (size_t)(i0 + row) * lda + k0 + scol);
      vb[rr] = *(const short8v*)(B + (size_t)(j0 + row) * ldb + k0 + scol);
    }
    __syncthreads();
#pragma unroll
    for (int rr = 0; rr < 4; ++rr) {
      int row = srow + rr * 32;
      int sw = (row * 64 + scol) ^ ((row & 7) << 3);
      *(short8v*)&Asm[sw] = va[rr];
      *(short8v*)&Bsm[sw] = vb[rr];
    }
    __syncthreads();
    short8v af[4][2], bf2[4][2];
#pragma unroll
    for (int m = 0; m < 4; ++m)
#pragma unroll
      for (int kk = 0; kk < 2; ++kk) {
        int ar = wm * 64 + m * 16 + fr, kb = kk * 32 + fg * 8;
        af[m][kk] = *(const short8v*)&Asm[(ar * 64 + kb) ^ ((ar & 7) << 3)];
        int br = wn * 64 + m * 16 + fr;
        bf2[m][kk] = *(const short8v*)&Bsm[(br * 64 + kb) ^ ((br & 7) << 3)];
      }
#pragma unroll
    for (int m = 0; m < 4; ++m)
#pragma unroll
      for (int n = 0; n < 4; ++n)
#pragma unroll
        for (int kk = 0; kk < 2; ++kk)
          acc[m][n] = __builtin_amdgcn_mfma_f32_16x16x32_bf16(af[m][kk], bf2[n][kk],
                                                              acc[m][n], 0, 0, 0);
  }
  float tmx[4], tmn[4];
  double ts[4], ts2[4];
#pragma unroll
  for (int n = 0; n < 4; ++n) {
    tmx[n] = -3.0e38f; tmn[n] = 3.0e38f; ts[n] = 0.0; ts2[n] = 0.0;
#pragma unroll
    for (int m = 0; m < 4; ++m)
#pragma unroll
      for (int j = 0; j < 4; ++j) {
        float v = acc[m][n][j];
        tmx[n] = fmaxf(tmx[n], v); tmn[n] = fminf(tmn[n], v);
        ts[n] += (double)v; ts2[n] += (double)v * (double)v;
      }
  }
#pragma unroll
  for (int off = 16; off < 64; off <<= 1)
#pragma unroll
    for (int n = 0; n < 4; ++n) {
      tmx[n] = fmaxf(tmx[n], __shfl_xor(tmx[n], off));
      tmn[n] = fminf(tmn[n], __shfl_xor(tmn[n], off));
      ts[n] += __shfl_xor(ts[n], off);
      ts2[n] += __shfl_xor(ts2[n], off);
    }
  __shared__ float smx[2][128], smn[2][128];
  __shared__ double ssm[2][128], ssq[2][128];
  __syncthreads();
  if (fg == 0) {
#pragma unroll
    for (int n = 0; n < 4; ++n) {
      int c = wn * 64 + n * 16 + fr;
      smx[wm][c] = tmx[n]; smn[wm][c] = tmn[n];
      ssm[wm][c] = ts[n];  ssq[wm][c] = ts2[n];
    }
  }
  __syncthreads();
  if (t < 128) {
    size_t base = (size_t)blockIdx.x * 1024 + j0 + t;
    pmx[base] = fmaxf(smx[0][t], smx[1][t]);
    pmn[base] = fminf(smn[0][t], smn[1][t]);
    psum[base] = ssm[0][t] + ssm[1][t];
    psq[base]  = ssq[0][t] + ssq[1][t];
  }
}

// ============ reduce conv5 tile partials ============
__global__ __launch_bounds__(256) void c5red_k(const float* __restrict__ pmx,
                                               const float* __restrict__ pmn,
                                               const double* __restrict__ psum,
                                               const double* __restrict__ psq,
                                               float* __restrict__ mx5, float* __restrict__ mn5,
                                               double* __restrict__ sums) {
  int gid = blockIdx.x * 256 + threadIdx.x;
  if (gid >= BB * 1024) return;
  int b = gid >> 10, o = gid & 1023;
  float mx = -3.0e38f, mn = 3.0e38f;
  double s = 0.0, s2 = 0.0;
#pragma unroll
  for (int ti = 0; ti < 16; ++ti) {
    size_t i = (size_t)(b * 16 + ti) * 1024 + o;
    mx = fmaxf(mx, pmx[i]); mn = fminf(mn, pmn[i]);
    s += psum[i]; s2 += psq[i];
  }
  mx5[gid] = mx; mn5[gid] = mn;
  atomicAdd(&sums[o], s);
  atomicAdd(&sums[1024 + o], s2);
}

// ============ weight transform: Wmod = [W_L ; W_R - W_L] (+ bf16 hi/lo planes) ============
__global__ __launch_bounds__(256) void wmod_k(const float* __restrict__ W, int O, int Cin,
                                              float* __restrict__ Wm,
                                              __hip_bfloat16* __restrict__ Wmh,
                                              __hip_bfloat16* __restrict__ Wml) {
  int i = blockIdx.x * 256 + threadIdx.x;
  if (i >= O * Cin) return;
  int o = i / Cin, c = i % Cin;
  float wl = W[(size_t)o * 2 * Cin + c];
  float wr = W[(size_t)o * 2 * Cin + Cin + c];
  float d = wr - wl;
  size_t iL = (size_t)o * Cin + c;
  size_t iR = (size_t)(O + o) * Cin + c;
  Wm[iL] = wl;
  Wm[iR] = d;
  __hip_bfloat16 hL = __float2bfloat16(wl);
  __hip_bfloat16 hR = __float2bfloat16(d);
  Wmh[iL] = hL; Wml[iL] = __float2bfloat16(wl - __bfloat162float(hL));
  Wmh[iR] = hR; Wml[iR] = __float2bfloat16(d - __bfloat162float(hR));
}

// ============ fp32 -> bf16 convert ============
__global__ __launch_bounds__(256) void tobf16_k(const float* __restrict__ in, int n,
                                                __hip_bfloat16* __restrict__ outv) {
  int i = blockIdx.x * 256 + threadIdx.x;
  if (i < n) outv[i] = __float2bfloat16(in[i]);
}

// ============ edge epilogue v3: float4 gather, full-k per thread, PPB points/block ============
// Thread owns (point-slot, 4-channel quad); loops over all KK neighbors in regs.
// max/min fully in registers (identical values to v2); fp64 sums reduced across slots.
template <int O, int PPB>
__global__ __launch_bounds__(256) void edgeep3_k(
    const float* __restrict__ z, const int* __restrict__ idx,
    float* __restrict__ hmax, float* __restrict__ hmin,
    double* __restrict__ partials)
{
  constexpr int TPP = O / 4;           // threads per point
  constexpr int PTS = 256 / TPP;       // points in flight
  const int ZW = 2 * O;
  int p0 = blockIdx.x * PPB;
  int t = threadIdx.x;
  int slot = t / TPP;
  int lc = t % TPP;
  int co = lc * 4;
  __shared__ int nb[PPB][KK];
  __shared__ double SS[2][256][4];     // 16 KB: per-thread 4-channel sum/sumsq
  for (int e = t; e < PPB * KK; e += 256) nb[e / KK][e % KK] = idx[(size_t)p0 * KK + e];
  __syncthreads();
  double s0 = 0.0, s1 = 0.0, s2 = 0.0, s3 = 0.0;
  double q0 = 0.0, q1 = 0.0, q2 = 0.0, q3 = 0.0;
#pragma unroll
  for (int it = 0; it < PPB / PTS; ++it) {
    int pi = it * PTS + slot;
    int p = p0 + pi;
    int b = p >> 11;
    float4 u4 = *(const float4*)&z[(size_t)p * ZW + O + co];
    float mx0 = -3.0e38f, mx1 = -3.0e38f, mx2 = -3.0e38f, mx3 = -3.0e38f;
    float mn0 = 3.0e38f, mn1 = 3.0e38f, mn2 = 3.0e38f, mn3 = 3.0e38f;
#pragma unroll
    for (int kk = 0; kk < KK; ++kk) {
      int q = nb[pi][kk];
      float4 y4 = *(const float4*)&z[((size_t)(b * NN + q)) * ZW + co];
      float h0 = u4.x + y4.x, h1 = u4.y + y4.y, h2 = u4.z + y4.z, h3 = u4.w + y4.w;
      mx0 = fmaxf(mx0, h0); mn0 = fminf(mn0, h0);
      mx1 = fmaxf(mx1, h1); mn1 = fminf(mn1, h1);
      mx2 = fmaxf(mx2, h2); mn2 = fminf(mn2, h2);
      mx3 = fmaxf(mx3, h3); mn3 = fminf(mn3, h3);
      s0 += (double)h0; q0 += (double)h0 * (double)h0;
      s1 += (double)h1; q1 += (double)h1 * (double)h1;
      s2 += (double)h2; q2 += (double)h2 * (double)h2;
      s3 += (double)h3; q3 += (double)h3 * (double)h3;
    }
    *(float4*)&hmax[(size_t)p * O + co] = float4{mx0, mx1, mx2, mx3};
    *(float4*)&hmin[(size_t)p * O + co] = float4{mn0, mn1, mn2, mn3};
  }
  SS[0][t][0] = s0; SS[0][t][1] = s1; SS[0][t][2] = s2; SS[0][t][3] = s3;
  SS[1][t][0] = q0; SS[1][t][1] = q1; SS[1][t][2] = q2; SS[1][t][3] = q3;
  __syncthreads();
  if (slot == 0) {
    double a0 = 0.0, a1 = 0.0, a2 = 0.0, a3 = 0.0;
    double b0 = 0.0, b1 = 0.0, b2 = 0.0, b3 = 0.0;
#pragma unroll
    for (int sl = 0; sl < PTS; ++sl) {
      int tt = sl * TPP + lc;
      a0 += SS[0][tt][0]; a1 += SS[0][tt][1]; a2 += SS[0][tt][2]; a3 += SS[0][tt][3];
      b0 += SS[1][tt][0]; b1 += SS[1][tt][1]; b2 += SS[1][tt][2]; b3 += SS[1][tt][3];
    }
    double* pp = partials + (size_t)blockIdx.x * (2 * O);
    pp[co + 0] = a0; pp[co + 1] = a1; pp[co + 2] = a2; pp[co + 3] = a3;
    pp[O + co + 0] = b0; pp[O + co + 1] = b1; pp[O + co + 2] = b2; pp[O + co + 3] = b3;
  }
}

// ============ reduce per-block partials -> sums ============
__global__ __launch_bounds__(256) void redsums_k(const double* __restrict__ P, int nblk,
                                                 int twoO, double* __restrict__ sums) {
  int j = blockIdx.x;
  int t = threadIdx.x;
  double s = 0.0;
  for (int b = t; b < nblk; b += 256) s += P[(size_t)b * twoO + j];
  __shared__ double L[256];
  L[t] = s; __syncthreads();
  for (int st = 128; st > 0; st >>= 1) {
    if (t < st) L[t] += L[t + st];
    __syncthreads();
  }
  if (t == 0) {
    int O = twoO >> 1;
    sums[j < O ? j : 1024 + (j - O)] = L[0];
  }
}

// ============ BN scale/shift from fp64 sums ============
__global__ __launch_bounds__(256) void mkscale_k(const double* __restrict__ sums,
                                                 const float* __restrict__ gam,
                                                 const float* __restrict__ bet,
                                                 int O, double invM,
                                                 float* __restrict__ scale,
                                                 float* __restrict__ shift) {
  int o = blockIdx.x * 256 + threadIdx.x;
  if (o >= O) return;
  double mean = sums[o] * invM;
  double var = sums[1024 + o] * invM - mean * mean;
  if (var < 0.0) var = 0.0;
  double r = 1.0 / sqrt(var + 1e-5);
  double s = (double)gam[o] * r;
  scale[o] = (float)s;
  shift[o] = (float)((double)bet[o] - mean * s);
}

// ============ apply BN + LeakyReLU via max/min; emits fp32 + bf16 hi + bf16 lo ============
__global__ __launch_bounds__(256) void apply_k(const float* __restrict__ hmax,
                                               const float* __restrict__ hmin,
                                               const float* __restrict__ scale,
                                               const float* __restrict__ shift,
                                               float* __restrict__ outb,
                                               __hip_bfloat16* __restrict__ outhi,
                                               __hip_bfloat16* __restrict__ outlo,
                                               int O, int ostride) {
  int gid = blockIdx.x * 256 + threadIdx.x;
  if (gid >= BB * NN * O) return;
  int p = gid / O, o = gid % O;
  float sc = scale[o];
  float v = (sc >= 0.f ? hmax[gid] : hmin[gid]) * sc + shift[o];
  float r = v >= 0.f ? v : 0.2f * v;
  __hip_bfloat16 hi = __float2bfloat16(r);
  float lo = r - __bfloat162float(hi);
  outb[(size_t)p * ostride + o] = r;
  outhi[(size_t)p * ostride + o] = hi;
  outlo[(size_t)p * ostride + o] = __float2bfloat16(lo);
}

// ============ final output ============
__global__ __launch_bounds__(256) void c5out_k(const float* __restrict__ mx5,
                                               const float* __restrict__ mn5,
                                               const float* __restrict__ scale,
                                               const float* __restrict__ shift,
                                               float* __restrict__ out) {
  int i = blockIdx.x * 256 + threadIdx.x;
  if (i >= BB * 1024) return;
  int o = i % 1024;
  float sc = scale[o];
  float v = (sc >= 0.f ? mx5[i] : mn5[i]) * sc + shift[o];
  out[i] = v >= 0.f ? v : 0.2f * v;
}

extern "C" void kernel_launch(void* const* d_in, const int* in_sizes, int n_in,
                              void* d_out, int out_size, void* d_ws, size_t ws_size,
                              hipStream_t stream) {
  const float* x  = (const float*)d_in[0];
  const float* W1 = (const float*)d_in[1];
  const float* g1 = (const float*)d_in[2];
  const float* b1 = (const float*)d_in[3];
  const float* W2 = (const float*)d_in[4];
  const float* g2 = (const float*)d_in[5];
  const float* b2 = (const float*)d_in[6];
  const float* W3 = (const float*)d_in[7];
  const float* g3 = (const float*)d_in[8];
  const float* b3 = (const float*)d_in[9];
  const float* W4 = (const float*)d_in[10];
  const float* g4 = (const float*)d_in[11];
  const float* b4 = (const float*)d_in[12];
  const float* W5 = (const float*)d_in[13];
  const float* g5 = (const float*)d_in[14];
  const float* b5 = (const float*)d_in[15];
  float* out = (float*)d_out;

  char* base = (char*)d_ws;
  size_t off = 0;
  auto alloc = [&](size_t nbytes) -> void* {
    void* p = (void*)(base + off);
    off += (nbytes + 255) & ~(size_t)255;
    return p;
  };
  float*  xxf   = (float*)alloc((size_t)BB * NN * 4);
  int*    idx   = (int*)alloc((size_t)BB * NN * KK * 4);
  int*    cand  = (int*)alloc((size_t)BB * NN * KSEL * 4);
  float*  scale = (float*)alloc(1024 * 4);
  float*  shift = (float*)alloc(1024 * 4);
  double* sums  = (double*)alloc(2048 * 8);
  float*  mx5   = (float*)alloc(8192 * 4);
  float*  mn5   = (float*)alloc(8192 * 4);
  float*  pmx   = (float*)alloc((size_t)128 * 1024 * 4);
  float*  pmn   = (float*)alloc((size_t)128 * 1024 * 4);
  double* psum  = (double*)alloc((size_t)128 * 1024 * 8);
  double* psq   = (double*)alloc((size_t)128 * 1024 * 8);
  float*  wmod  = (float*)alloc((size_t)512 * 128 * 4);
  __hip_bfloat16* wmodh = (__hip_bfloat16*)alloc((size_t)512 * 128 * 2);
  __hip_bfloat16* wmodl = (__hip_bfloat16*)alloc((size_t)512 * 128 * 2);
  __hip_bfloat16* w5b = (__hip_bfloat16*)alloc((size_t)1024 * 512 * 2);
  double* parts = (double*)alloc((size_t)1024 * 512 * 8);
  float*  xcat  = (float*)alloc((size_t)BB * NN * 512 * 4);
  __hip_bfloat16* xcatb  = (__hip_bfloat16*)alloc((size_t)BB * NN * 512 * 2);
  __hip_bfloat16* xcatlo = (__hip_bfloat16*)alloc((size_t)BB * NN * 512 * 2);
  float*  hmax  = (float*)alloc((size_t)BB * NN * 256 * 4);
  float*  hmin  = (float*)alloc((size_t)BB * NN * 256 * 4);
  size_t zoff = off;
  float*  zar   = (float*)alloc((size_t)BB * NN * 1024 * 4);  // z arena
  float*  dist  = (float*)zar;   // fp32 dist aliases zar (pd/topk finish before z written)
  size_t avail = (ws_size > zoff) ? (ws_size - zoff) : ((size_t)BB * NN * 1024 * 4);
  int CB = (int)(avail / ((size_t)NN * NN * 4));
  if (CB > BB) CB = BB;
  if (CB < 1) CB = 1;

  const int PPB = 16;
  const int NBLK = BB * NN / PPB;  // 1024

  auto run_layer = [&](const float* xin, const __hip_bfloat16* xinh,
                       const __hip_bfloat16* xinl, int stride, int Cin, int O,
                       const float* W, const float* gg, const float* bbeta,
                       int ooff, int variant) {
    // ---- kNN: select top-32 candidates + fp64 refine (top-20 exact) ----
    if (Cin == 3) {
      knn3_k<<<BB * NN / 16, 256, 0, stream>>>(xin, cand);
    } else {
      norms_k<<<64, 256, 0, stream>>>(xin, Cin, stride, xxf);
      for (int b0 = 0; b0 < BB; b0 += CB) {
        int cb = BB - b0; if (cb > CB) cb = CB;
        dim3 gpd(16, 16, cb);
        pdmfma_k<<<gpd, 512, 0, stream>>>(
            (const unsigned short*)xinh + (size_t)b0 * NN * stride,
            (const unsigned short*)xinl + (size_t)b0 * NN * stride,
            stride, (long long)NN * stride,
            dist, xxf + (size_t)b0 * NN, Cin);
        topk32_k<<<cb * 512, 256, 0, stream>>>(dist, b0 * NN, cand);
      }
    }
    if (Cin == 3)
      refine4_k<3><<<BB * NN / 4, 256, 0, stream>>>(xin, stride, cand, idx);
    else if (Cin == 64)
      refine4_k<64><<<BB * NN / 4, 256, 0, stream>>>(xin, stride, cand, idx);
    else
      refine4_k<128><<<BB * NN / 4, 256, 0, stream>>>(xin, stride, cand, idx);
    // ---- point-level GEMM: z = xin * [W_L ; W_R - W_L]^T ----
    wmod_k<<<(O * Cin + 255) / 256, 256, 0, stream>>>(W, O, Cin, wmod, wmodh, wmodl);
    if (Cin == 3) {
      dim3 gf(128, (2 * O) / 128, 1);
      gemm128_k<<<gf, 256, 0, stream>>>(xin, stride, wmod, Cin, zar, 2 * O, Cin);
    } else {
      dim3 gf(128, (2 * O) / 128, 1);
      gemm_fb_k<<<gf, 512, 0, stream>>>(
          (const unsigned short*)xinh, (const unsigned short*)xinl, stride,
          (const unsigned short*)wmodh, (const unsigned short*)wmodl, Cin,
          zar, 2 * O, Cin);
    }
    // ---- gather-reduce epilogue ----
    if (variant == 0)
      edgeep3_k<64, PPB><<<NBLK, 256, 0, stream>>>(zar, idx, hmax, hmin, parts);
    else if (variant == 1)
      edgeep3_k<128, PPB><<<NBLK, 256, 0, stream>>>(zar, idx, hmax, hmin, parts);
    else
      edgeep3_k<256, PPB><<<NBLK, 256, 0, stream>>>(zar, idx, hmax, hmin, parts);
    redsums_k<<<2 * O, 256, 0, stream>>>(parts, NBLK, 2 * O, sums);
    mkscale_k<<<(O + 255) / 256, 256, 0, stream>>>(
        sums, gg, bbeta, O, 1.0 / ((double)BB * NN * KK), scale, shift);
    apply_k<<<(BB * NN * O + 255) / 256, 256, 0, stream>>>(
        hmax, hmin, scale, shift, xcat + ooff, xcatb + ooff, xcatlo + ooff, O, 512);
  };

  run_layer(x,          nullptr,      nullptr,       3,   3,   64,  W1, g1, b1, 0,   0);
  run_layer(xcat + 0,   xcatb + 0,    xcatlo + 0,    512, 64,  64,  W2, g2, b2, 64,  0);
  run_layer(xcat + 64,  xcatb + 64,   xcatlo + 64,   512, 64,  128, W3, g3, b3, 128, 1);
  run_layer(xcat + 128, xcatb + 128,  xcatlo + 128,  512, 128, 256, W4, g4, b4, 256, 2);

  // conv5 via bf16 MFMA with fused stats (no h materialization)
  tobf16_k<<<(1024 * 512 + 255) / 256, 256, 0, stream>>>(W5, 1024 * 512, w5b);
  dim3 g5d(128, 8, 1);
  gemm_c5_k<<<g5d, 256, 0, stream>>>((const unsigned short*)xcatb, 512,
                                     (const unsigned short*)w5b, 512,
                                     pmx, pmn, psum, psq, 512);
  hipMemsetAsync(sums, 0, 2048 * 8, stream);
  c5red_k<<<32, 256, 0, stream>>>(pmx, pmn, psum, psq, mx5, mn5, sums);
  mkscale_k<<<4, 256, 0, stream>>>(sums, g5, b5, 1024, 1.0 / ((double)BB * NN),
                                   scale, shift);
  c5out_k<<<32, 256, 0, stream>>>(mx5, mn5, scale, shift, out);
}

// Round 21
// 547.397 us; speedup vs baseline: 1.0519x; 1.0519x over previous
//
#include <hip/hip_runtime.h>
#include <hip/hip_bf16.h>

#define BB 8
#define NN 2048
#define KK 20
#define KSEL 32
#define SCAP 256

typedef __attribute__((ext_vector_type(8))) short short8v;   // 8 bf16 (4 VGPR)
typedef __attribute__((ext_vector_type(4))) float f32x4;

// ============ per-point squared norms (fp64 acc, fp32 out) ============
__global__ __launch_bounds__(256) void norms_k(const float* __restrict__ xin, int C, int stride,
                                               float* __restrict__ xx) {
  int p = blockIdx.x * 256 + threadIdx.x;
  if (p >= BB * NN) return;
  const float* r = xin + (size_t)p * stride;
  double s = 0.0;
  for (int c = 0; c < C; ++c) { double v = (double)r[c]; s += v * v; }
  xx[p] = (float)s;
}

// ============ fallback: full ballot bit-search (verified semantics) ============
__device__ __forceinline__ void bitsel_fallback(unsigned (&u)[32], int lane,
                                                int* __restrict__ outp)
{
  unsigned long long lmask = (1ull << lane) - 1ull;
  unsigned T = 0;
  bool exact = false;
  for (int b = 31; b >= 0; --b) {
    unsigned Tp = T | (1u << b);
    int cnt = 0;
#pragma unroll
    for (int q = 0; q < 32; ++q)
      cnt += __popcll(__ballot(u[q] >= Tp));
    if (cnt >= KSEL) {
      T = Tp;
      if (cnt == KSEL) { exact = true; break; }
    }
  }
  int cnt = 0;
#pragma unroll
  for (int q = 0; q < 32; ++q) {
    bool take = exact ? (u[q] >= T) : (u[q] > T);
    unsigned long long m = __ballot(take);
    if (take) outp[cnt + __popcll(m & lmask)] = lane + 64 * q;
    cnt += __popcll(m);
  }
  if (!exact) {
    int tneed = KSEL - cnt;
#pragma unroll
    for (int q = 0; q < 32; ++q) {
      if (tneed > 0) {
        bool eq = (u[q] == T);
        unsigned long long m = __ballot(eq);
        int before = __popcll(m & lmask);
        if (eq && before < tneed) outp[cnt + before] = lane + 64 * q;
        int c = __popcll(m);
        int used = c < tneed ? c : tneed;
        cnt += used; tneed -= used;
      }
    }
  }
}

// ============ threshold+compaction top-KSEL select (wave-local, no atomics) ============
__device__ __forceinline__ void thresel32(unsigned (&u)[32], int lane,
                                          unsigned* __restrict__ cv, int* __restrict__ ci,
                                          int* __restrict__ outp)
{
  unsigned long long lmask = (1ull << lane) - 1ull;
  unsigned lm = u[0];
#pragma unroll
  for (int q = 1; q < 32; ++q) lm = u[q] > lm ? u[q] : lm;
  unsigned T = 0;
  for (int b = 31; b >= 0; --b) {
    unsigned Tp = T | (1u << b);
    int c = __popcll(__ballot(lm >= Tp));
    if (c >= 32) { T = Tp; if (c == 32) break; }
  }
  int n0 = 0;
#pragma unroll
  for (int q = 0; q < 32; ++q) n0 += __popcll(__ballot(u[q] >= T));
  if (n0 <= SCAP) {
    int cnt = 0;
#pragma unroll
    for (int q = 0; q < 32; ++q) {
      bool take = u[q] >= T;
      unsigned long long m = __ballot(take);
      if (take) {
        int pos = cnt + __popcll(m & lmask);
        cv[pos] = u[q];
        ci[pos] = lane + 64 * q;
      }
      cnt += __popcll(m);
    }
    for (int i = lane; i < n0; i += 64) {
      unsigned vi = cv[i];
      int rank = 0;
      for (int j = 0; j < n0; ++j) {
        unsigned vj = cv[j];
        rank += (vj > vi || (vj == vi && j < i)) ? 1 : 0;
      }
      if (rank < KSEL) outp[rank] = ci[i];
    }
  } else {
    bitsel_fallback(u, lane, outp);
  }
}

// ============ layer-1 fused kNN (C=3): direct distances from LDS ============
__global__ __launch_bounds__(256) void knn3_k(const float* __restrict__ xin,
                                              int* __restrict__ cand)
{
  int t = threadIdx.x;
  int wv = t >> 6, lane = t & 63;
  const int BPB = NN / 16;
  int b = blockIdx.x / BPB;
  int p0 = (blockIdx.x % BPB) * 16;
  __shared__ float xs[3][NN];
  __shared__ unsigned cvs[4][SCAP];
  __shared__ int cis[4][SCAP];
  const float* xb = xin + (size_t)b * NN * 3;
  for (int e = t; e < NN * 3; e += 256) xs[e % 3][e / 3] = xb[e];
  __syncthreads();
  for (int rr = 0; rr < 4; ++rr) {
    int row = p0 + wv * 4 + rr;
    float xi0 = xs[0][row], xi1 = xs[1][row], xi2 = xs[2][row];
    unsigned u[32];
#pragma unroll
    for (int q = 0; q < 32; ++q) {
      int j = lane + 64 * q;
      float d0 = xi0 - xs[0][j], d1 = xi1 - xs[1][j], d2 = xi2 - xs[2][j];
      float v = -(d0 * d0 + d1 * d1 + d2 * d2);
      unsigned bb = __float_as_uint(v);
      u[q] = bb ^ (((unsigned)((int)bb >> 31)) | 0x80000000u);
    }
    thresel32(u, lane, cvs[wv], cis[wv], cand + ((size_t)(b * NN + row)) * KSEL);
  }
}

// ============ pd via split-bf16 MFMA (layers 2-4): D = 2*(hh+hl+lh) - xx_i - xx_j ============
// 512 threads / 8 waves, 128x128 tile, BK=64 (replay-verified round 18).
__global__ __launch_bounds__(512) void pdmfma_k(
    const unsigned short* __restrict__ Ah, const unsigned short* __restrict__ Al,
    int lda, long long az,
    float* __restrict__ D, const float* __restrict__ xx, int Kd)
{
  __shared__ unsigned short AsH[128 * 64];
  __shared__ unsigned short AsL[128 * 64];
  __shared__ unsigned short BsH[128 * 64];
  __shared__ unsigned short BsL[128 * 64];
  int z = blockIdx.z;
  const unsigned short* Ahb = Ah + az * z;
  const unsigned short* Alb = Al + az * z;
  float* Db = D + (size_t)NN * NN * z;
  const float* xxb = xx + (size_t)NN * z;
  int t = threadIdx.x;
  int w = t >> 6, lane = t & 63;
  int wm = w >> 2, wn = w & 3;
  int i0 = blockIdx.x * 128, j0 = blockIdx.y * 128;
  int fr = lane & 15, fg = lane >> 4;
  int srow = t >> 3;
  int scol = (t & 7) * 8;
  f32x4 acc[4][2] = {};
  for (int k0 = 0; k0 < Kd; k0 += 64) {
    short8v vah[2], valo[2], vbh[2], vbl[2];
#pragma unroll
    for (int rr = 0; rr < 2; ++rr) {
      int row = srow + rr * 64;
      vah[rr]  = *(const short8v*)(Ahb + (size_t)(i0 + row) * lda + k0 + scol);
      valo[rr] = *(const short8v*)(Alb + (size_t)(i0 + row) * lda + k0 + scol);
      vbh[rr]  = *(const short8v*)(Ahb + (size_t)(j0 + row) * lda + k0 + scol);
      vbl[rr]  = *(const short8v*)(Alb + (size_t)(j0 + row) * lda + k0 + scol);
    }
    __syncthreads();
#pragma unroll
    for (int rr = 0; rr < 2; ++rr) {
      int row = srow + rr * 64;
      int sw = (row * 64 + scol) ^ ((row & 7) << 3);
      *(short8v*)&AsH[sw] = vah[rr];
      *(short8v*)&AsL[sw] = valo[rr];
      *(short8v*)&BsH[sw] = vbh[rr];
      *(short8v*)&BsL[sw] = vbl[rr];
    }
    __syncthreads();
#pragma unroll
    for (int kk = 0; kk < 2; ++kk) {
      short8v ah[4], al[4], bh[2], bl[2];
      int kb = kk * 32 + fg * 8;
#pragma unroll
      for (int m = 0; m < 4; ++m) {
        int ar = wm * 64 + m * 16 + fr;
        int ai = (ar * 64 + kb) ^ ((ar & 7) << 3);
        ah[m] = *(const short8v*)&AsH[ai];
        al[m] = *(const short8v*)&AsL[ai];
      }
#pragma unroll
      for (int n = 0; n < 2; ++n) {
        int br = wn * 32 + n * 16 + fr;
        int bi = (br * 64 + kb) ^ ((br & 7) << 3);
        bh[n] = *(const short8v*)&BsH[bi];
        bl[n] = *(const short8v*)&BsL[bi];
      }
#pragma unroll
      for (int m = 0; m < 4; ++m)
#pragma unroll
        for (int n = 0; n < 2; ++n) {
          acc[m][n] = __builtin_amdgcn_mfma_f32_16x16x32_bf16(ah[m], bh[n], acc[m][n], 0, 0, 0);
          acc[m][n] = __builtin_amdgcn_mfma_f32_16x16x32_bf16(ah[m], bl[n], acc[m][n], 0, 0, 0);
          acc[m][n] = __builtin_amdgcn_mfma_f32_16x16x32_bf16(al[m], bh[n], acc[m][n], 0, 0, 0);
        }
    }
    __syncthreads();
  }
#pragma unroll
  for (int m = 0; m < 4; ++m) {
    float xi[4];
#pragma unroll
    for (int j = 0; j < 4; ++j) xi[j] = xxb[i0 + wm * 64 + m * 16 + fg * 4 + j];
#pragma unroll
    for (int n = 0; n < 2; ++n) {
      float xj = xxb[j0 + wn * 32 + n * 16 + fr];
#pragma unroll
      for (int j = 0; j < 4; ++j)
        Db[(size_t)(i0 + wm * 64 + m * 16 + fg * 4 + j) * NN +
           j0 + wn * 32 + n * 16 + fr] = 2.f * acc[m][n][j] - xi[j] - xj;
    }
  }
}

// ============ feature GEMM via split-bf16 MFMA (layers 2-4): Z = X * Wmod^T ============
__global__ __launch_bounds__(512) void gemm_fb_k(
    const unsigned short* __restrict__ Ah, const unsigned short* __restrict__ Al, int lda,
    const unsigned short* __restrict__ Bh, const unsigned short* __restrict__ Bl, int ldb,
    float* __restrict__ C, int ldc, int Kd)
{
  __shared__ unsigned short AsH[128 * 64];
  __shared__ unsigned short AsL[128 * 64];
  __shared__ unsigned short BsH[128 * 64];
  __shared__ unsigned short BsL[128 * 64];
  int t = threadIdx.x;
  int w = t >> 6, lane = t & 63;
  int wm = w >> 2, wn = w & 3;
  int i0 = blockIdx.x * 128, j0 = blockIdx.y * 128;
  int fr = lane & 15, fg = lane >> 4;
  int srow = t >> 3;
  int scol = (t & 7) * 8;
  f32x4 acc[4][2] = {};
  for (int k0 = 0; k0 < Kd; k0 += 64) {
    short8v vah[2], valo[2], vbh[2], vbl[2];
#pragma unroll
    for (int rr = 0; rr < 2; ++rr) {
      int row = srow + rr * 64;
      vah[rr]  = *(const short8v*)(Ah + (size_t)(i0 + row) * lda + k0 + scol);
      valo[rr] = *(const short8v*)(Al + (size_t)(i0 + row) * lda + k0 + scol);
      vbh[rr]  = *(const short8v*)(Bh + (size_t)(j0 + row) * ldb + k0 + scol);
      vbl[rr]  = *(const short8v*)(Bl + (size_t)(j0 + row) * ldb + k0 + scol);
    }
    __syncthreads();
#pragma unroll
    for (int rr = 0; rr < 2; ++rr) {
      int row = srow + rr * 64;
      int sw = (row * 64 + scol) ^ ((row & 7) << 3);
      *(short8v*)&AsH[sw] = vah[rr];
      *(short8v*)&AsL[sw] = valo[rr];
      *(short8v*)&BsH[sw] = vbh[rr];
      *(short8v*)&BsL[sw] = vbl[rr];
    }
    __syncthreads();
#pragma unroll
    for (int kk = 0; kk < 2; ++kk) {
      short8v ah[4], al[4], bh[2], bl[2];
      int kb = kk * 32 + fg * 8;
#pragma unroll
      for (int m = 0; m < 4; ++m) {
        int ar = wm * 64 + m * 16 + fr;
        int ai = (ar * 64 + kb) ^ ((ar & 7) << 3);
        ah[m] = *(const short8v*)&AsH[ai];
        al[m] = *(const short8v*)&AsL[ai];
      }
#pragma unroll
      for (int n = 0; n < 2; ++n) {
        int br = wn * 32 + n * 16 + fr;
        int bi = (br * 64 + kb) ^ ((br & 7) << 3);
        bh[n] = *(const short8v*)&BsH[bi];
        bl[n] = *(const short8v*)&BsL[bi];
      }
#pragma unroll
      for (int m = 0; m < 4; ++m)
#pragma unroll
        for (int n = 0; n < 2; ++n) {
          acc[m][n] = __builtin_amdgcn_mfma_f32_16x16x32_bf16(ah[m], bh[n], acc[m][n], 0, 0, 0);
          acc[m][n] = __builtin_amdgcn_mfma_f32_16x16x32_bf16(ah[m], bl[n], acc[m][n], 0, 0, 0);
          acc[m][n] = __builtin_amdgcn_mfma_f32_16x16x32_bf16(al[m], bh[n], acc[m][n], 0, 0, 0);
        }
    }
    __syncthreads();
  }
#pragma unroll
  for (int m = 0; m < 4; ++m)
#pragma unroll
    for (int n = 0; n < 2; ++n)
#pragma unroll
      for (int j = 0; j < 4; ++j)
        C[(size_t)(i0 + wm * 64 + m * 16 + fg * 4 + j) * ldc +
          j0 + wn * 32 + n * 16 + fr] = acc[m][n][j];
}

// ============ top-KSEL candidates per row, one wave per row ============
__global__ __launch_bounds__(256) void topk32_k(const float* __restrict__ dist, int row0,
                                                int* __restrict__ cand)
{
  int wv = threadIdx.x >> 6;
  int row = blockIdx.x * 4 + wv;
  int lane = threadIdx.x & 63;
  const float* d = dist + (size_t)row * NN;
  unsigned u[32];
#pragma unroll
  for (int q = 0; q < 32; ++q) {
    unsigned b = __float_as_uint(d[lane + 64 * q]);
    unsigned mk = ((unsigned)((int)b >> 31)) | 0x80000000u;
    u[q] = b ^ mk;
  }
  __shared__ unsigned cvs[4][SCAP];
  __shared__ int cis[4][SCAP];
  thresel32(u, lane, cvs[wv], cis[wv], cand + (size_t)(row0 + row) * KSEL);
}

// ============ refine v4: templated C -> fully unrolled gather (max load ILP) ============
template <int C>
__global__ __launch_bounds__(256) void refine4_k(const float* __restrict__ xin, int stride,
                                                 const int* __restrict__ cand,
                                                 int* __restrict__ idxout)
{
  int t = threadIdx.x;
  int w = t >> 6, lane = t & 63;
  int p = blockIdx.x * 4 + w;
  int b = p >> 11;
  __shared__ float xi[4][C < 4 ? 4 : C];
  __shared__ double Lval[4][KSEL];
  __shared__ int Lidx[4][KSEL];
#pragma unroll
  for (int c = lane; c < C; c += 64) xi[w][c] = xin[(size_t)p * stride + c];
  __syncthreads();
  int m = lane >> 1, h = lane & 1;
  int q = cand[(size_t)p * KSEL + m];
  const float* xr = xin + (size_t)(b * NN + q) * stride;
  double s;
  if constexpr (C >= 8) {
    constexpr int half = C >> 1;
    int c0 = h * half;
    float4 v[half / 4];
#pragma unroll
    for (int i = 0; i < half / 4; ++i) v[i] = *(const float4*)(xr + c0 + 4 * i);
    double a0 = 0.0, a1 = 0.0, a2 = 0.0, a3 = 0.0;
#pragma unroll
    for (int i = 0; i < half / 4; ++i) {
      float4 xv = *(const float4*)(&xi[w][c0 + 4 * i]);
      double d0 = (double)xv.x - (double)v[i].x;
      double d1 = (double)xv.y - (double)v[i].y;
      double d2 = (double)xv.z - (double)v[i].z;
      double d3 = (double)xv.w - (double)v[i].w;
      a0 += d0 * d0; a1 += d1 * d1; a2 += d2 * d2; a3 += d3 * d3;
    }
    s = (a0 + a1) + (a2 + a3);
  } else {
    s = 0.0;
#pragma unroll
    for (int c = h; c < C; c += 2) {
      double d = (double)xi[w][c] - (double)xr[c];
      s += d * d;
    }
  }
  s += __shfl_xor(s, 1);
  if (h == 0) { Lval[w][m] = -s; Lidx[w][m] = q; }
  __syncthreads();
  int mm = lane & 31;
  double vm = Lval[w][mm];
  int im = Lidx[w][mm];
  int rank = 0;
#pragma unroll
  for (int j = 0; j < KSEL; ++j) {
    double vj = Lval[w][j];
    int ij = Lidx[w][j];
    rank += (vj > vm || (vj == vm && ij < im)) ? 1 : 0;
  }
  if (lane < 32 && rank < KK) idxout[(size_t)p * KK + rank] = im;
}

// ============ generic 128x128-tile fp32 GEMM: C = A * B^T (layer-1 feature GEMM) ============
__global__ __launch_bounds__(256) void gemm128_k(
    const float* __restrict__ A, int lda,
    const float* __restrict__ Bm, int ldb,
    float* __restrict__ C, int ldc, int Kd)
{
  __shared__ float As[128 * 68];
  __shared__ float Bs[128 * 68];
  int i0 = blockIdx.x * 128;
  int j0 = blockIdx.y * 128;
  int t = threadIdx.x;
  int tx = t & 15, ty = t >> 4;
  float acc[8][8] = {};
  for (int k0 = 0; k0 < Kd; k0 += 64) {
    int kt = Kd - k0; if (kt > 64) kt = 64;
    if (kt == 64) {
      for (int e = t; e < 128 * 64; e += 256) {
        int i = e >> 6, c = e & 63;
        As[i * 68 + c] = A[(size_t)(i0 + i) * lda + k0 + c];
        Bs[i * 68 + c] = Bm[(size_t)(j0 + i) * ldb + k0 + c];
      }
    } else {
      for (int e = t; e < 128 * kt; e += 256) {
        int i = e / kt, c = e % kt;
        As[i * 68 + c] = A[(size_t)(i0 + i) * lda + k0 + c];
        Bs[i * 68 + c] = Bm[(size_t)(j0 + i) * ldb + k0 + c];
      }
    }
    __syncthreads();
    int kt4 = kt & ~3;
    for (int c = 0; c < kt4; c += 4) {
      float4 a4[8], b4[8];
#pragma unroll
      for (int r = 0; r < 8; ++r) a4[r] = *(const float4*)&As[(ty + 16 * r) * 68 + c];
#pragma unroll
      for (int q = 0; q < 8; ++q) b4[q] = *(const float4*)&Bs[(tx + 16 * q) * 68 + c];
#pragma unroll
      for (int r = 0; r < 8; ++r)
#pragma unroll
        for (int q = 0; q < 8; ++q)
          acc[r][q] += a4[r].x * b4[q].x + a4[r].y * b4[q].y +
                       a4[r].z * b4[q].z + a4[r].w * b4[q].w;
    }
    for (int c = kt4; c < kt; ++c) {
      float av[8], bv[8];
#pragma unroll
      for (int r = 0; r < 8; ++r) av[r] = As[(ty + 16 * r) * 68 + c];
#pragma unroll
      for (int q = 0; q < 8; ++q) bv[q] = Bs[(tx + 16 * q) * 68 + c];
#pragma unroll
      for (int r = 0; r < 8; ++r)
#pragma unroll
        for (int q = 0; q < 8; ++q) acc[r][q] += av[r] * bv[q];
    }
    __syncthreads();
  }
#pragma unroll
  for (int r = 0; r < 8; ++r)
#pragma unroll
    for (int q = 0; q < 8; ++q)
      C[(size_t)(i0 + ty + 16 * r) * ldc + j0 + tx + 16 * q] = acc[r][q];
}

// ============ conv5 bf16 MFMA GEMM with FUSED stats epilogue (no C write) ============
__global__ __launch_bounds__(256) void gemm_c5_k(
    const unsigned short* __restrict__ A, int lda,
    const unsigned short* __restrict__ B, int ldb,
    float* __restrict__ pmx, float* __restrict__ pmn,
    double* __restrict__ psum, double* __restrict__ psq, int Kd)
{
  __shared__ unsigned short Asm[128 * 64];
  __shared__ unsigned short Bsm[128 * 64];
  int t = threadIdx.x;
  int w = t >> 6, lane = t & 63;
  int wm = w >> 1, wn = w & 1;
  int i0 = blockIdx.x * 128, j0 = blockIdx.y * 128;
  int fr = lane & 15, fg = lane >> 4;
  int srow = t >> 3;
  int scol = (t & 7) * 8;
  f32x4 acc[4][4] = {};
  for (int k0 = 0; k0 < Kd; k0 += 64) {
    short8v va[4], vb[4];
#pragma unroll
    for (int rr = 0; rr < 4; ++rr) {
      int row = srow + rr * 32;
      va[rr] = *(const short8v*)(A + (size_t)(i0 + row) * lda + k0 + scol);
      vb[rr] = *(const short8v*)(B + (size_t)(j0 + row) * ldb + k0 + scol);
    }
    __syncthreads();
#pragma unroll
    for (int rr = 0; rr < 4; ++rr) {
      int row = srow + rr * 32;
      int sw = (row * 64 + scol) ^ ((row & 7) << 3);
      *(short8v*)&Asm[sw] = va[rr];
      *(short8v*)&Bsm[sw] = vb[rr];
    }
    __syncthreads();
    short8v af[4][2], bf2[4][2];
#pragma unroll
    for (int m = 0; m < 4; ++m)
#pragma unroll
      for (int kk = 0; kk < 2; ++kk) {
        int ar = wm * 64 + m * 16 + fr, kb = kk * 32 + fg * 8;
        af[m][kk] = *(const short8v*)&Asm[(ar * 64 + kb) ^ ((ar & 7) << 3)];
        int br = wn * 64 + m * 16 + fr;
        bf2[m][kk] = *(const short8v*)&Bsm[(br * 64 + kb) ^ ((br & 7) << 3)];
      }
#pragma unroll
    for (int m = 0; m < 4; ++m)
#pragma unroll
      for (int n = 0; n < 4; ++n)
#pragma unroll
        for (int kk = 0; kk < 2; ++kk)
          acc[m][n] = __builtin_amdgcn_mfma_f32_16x16x32_bf16(af[m][kk], bf2[n][kk],
                                                              acc[m][n], 0, 0, 0);
  }
  float tmx[4], tmn[4];
  double ts[4], ts2[4];
#pragma unroll
  for (int n = 0; n < 4; ++n) {
    tmx[n] = -3.0e38f; tmn[n] = 3.0e38f; ts[n] = 0.0; ts2[n] = 0.0;
#pragma unroll
    for (int m = 0; m < 4; ++m)
#pragma unroll
      for (int j = 0; j < 4; ++j) {
        float v = acc[m][n][j];
        tmx[n] = fmaxf(tmx[n], v); tmn[n] = fminf(tmn[n], v);
        ts[n] += (double)v; ts2[n] += (double)v * (double)v;
      }
  }
#pragma unroll
  for (int off = 16; off < 64; off <<= 1)
#pragma unroll
    for (int n = 0; n < 4; ++n) {
      tmx[n] = fmaxf(tmx[n], __shfl_xor(tmx[n], off));
      tmn[n] = fminf(tmn[n], __shfl_xor(tmn[n], off));
      ts[n] += __shfl_xor(ts[n], off);
      ts2[n] += __shfl_xor(ts2[n], off);
    }
  __shared__ float smx[2][128], smn[2][128];
  __shared__ double ssm[2][128], ssq[2][128];
  __syncthreads();
  if (fg == 0) {
#pragma unroll
    for (int n = 0; n < 4; ++n) {
      int c = wn * 64 + n * 16 + fr;
      smx[wm][c] = tmx[n]; smn[wm][c] = tmn[n];
      ssm[wm][c] = ts[n];  ssq[wm][c] = ts2[n];
    }
  }
  __syncthreads();
  if (t < 128) {
    size_t base = (size_t)blockIdx.x * 1024 + j0 + t;
    pmx[base] = fmaxf(smx[0][t], smx[1][t]);
    pmn[base] = fminf(smn[0][t], smn[1][t]);
    psum[base] = ssm[0][t] + ssm[1][t];
    psq[base]  = ssq[0][t] + ssq[1][t];
  }
}

// ============ reduce conv5 tile partials ============
__global__ __launch_bounds__(256) void c5red_k(const float* __restrict__ pmx,
                                               const float* __restrict__ pmn,
                                               const double* __restrict__ psum,
                                               const double* __restrict__ psq,
                                               float* __restrict__ mx5, float* __restrict__ mn5,
                                               double* __restrict__ sums) {
  int gid = blockIdx.x * 256 + threadIdx.x;
  if (gid >= BB * 1024) return;
  int b = gid >> 10, o = gid & 1023;
  float mx = -3.0e38f, mn = 3.0e38f;
  double s = 0.0, s2 = 0.0;
#pragma unroll
  for (int ti = 0; ti < 16; ++ti) {
    size_t i = (size_t)(b * 16 + ti) * 1024 + o;
    mx = fmaxf(mx, pmx[i]); mn = fminf(mn, pmn[i]);
    s += psum[i]; s2 += psq[i];
  }
  mx5[gid] = mx; mn5[gid] = mn;
  atomicAdd(&sums[o], s);
  atomicAdd(&sums[1024 + o], s2);
}

// ============ weight transform: Wmod = [W_L ; W_R - W_L] (+ bf16 hi/lo planes) ============
__global__ __launch_bounds__(256) void wmod_k(const float* __restrict__ W, int O, int Cin,
                                              float* __restrict__ Wm,
                                              __hip_bfloat16* __restrict__ Wmh,
                                              __hip_bfloat16* __restrict__ Wml) {
  int i = blockIdx.x * 256 + threadIdx.x;
  if (i >= O * Cin) return;
  int o = i / Cin, c = i % Cin;
  float wl = W[(size_t)o * 2 * Cin + c];
  float wr = W[(size_t)o * 2 * Cin + Cin + c];
  float d = wr - wl;
  size_t iL = (size_t)o * Cin + c;
  size_t iR = (size_t)(O + o) * Cin + c;
  Wm[iL] = wl;
  Wm[iR] = d;
  __hip_bfloat16 hL = __float2bfloat16(wl);
  __hip_bfloat16 hR = __float2bfloat16(d);
  Wmh[iL] = hL; Wml[iL] = __float2bfloat16(wl - __bfloat162float(hL));
  Wmh[iR] = hR; Wml[iR] = __float2bfloat16(d - __bfloat162float(hR));
}

// ============ fp32 -> bf16 convert ============
__global__ __launch_bounds__(256) void tobf16_k(const float* __restrict__ in, int n,
                                                __hip_bfloat16* __restrict__ outv) {
  int i = blockIdx.x * 256 + threadIdx.x;
  if (i < n) outv[i] = __float2bfloat16(in[i]);
}

// ============ edge epilogue v3 + XCD-aware block swizzle ============
// Physical block bid runs logical chunk sw = (bid%8)*(nblk/8) + bid/8, so all
// blocks of one batch land on one XCD and its 4MB L2 holds that batch's z.
template <int O, int PPB>
__global__ __launch_bounds__(256) void edgeep3_k(
    const float* __restrict__ z, const int* __restrict__ idx,
    float* __restrict__ hmax, float* __restrict__ hmin,
    double* __restrict__ partials)
{
  constexpr int TPP = O / 4;           // threads per point
  constexpr int PTS = 256 / TPP;       // points in flight
  const int ZW = 2 * O;
  int nblk = gridDim.x;
  int bid = blockIdx.x;
  int sw = (bid & 7) * (nblk >> 3) + (bid >> 3);   // bijective (nblk % 8 == 0)
  int p0 = sw * PPB;
  int t = threadIdx.x;
  int slot = t / TPP;
  int lc = t % TPP;
  int co = lc * 4;
  __shared__ int nb[PPB][KK];
  __shared__ double SS[2][256][4];
  for (int e = t; e < PPB * KK; e += 256) nb[e / KK][e % KK] = idx[(size_t)p0 * KK + e];
  __syncthreads();
  double s0 = 0.0, s1 = 0.0, s2 = 0.0, s3 = 0.0;
  double q0 = 0.0, q1 = 0.0, q2 = 0.0, q3 = 0.0;
#pragma unroll
  for (int it = 0; it < PPB / PTS; ++it) {
    int pi = it * PTS + slot;
    int p = p0 + pi;
    int b = p >> 11;
    float4 u4 = *(const float4*)&z[(size_t)p * ZW + O + co];
    float mx0 = -3.0e38f, mx1 = -3.0e38f, mx2 = -3.0e38f, mx3 = -3.0e38f;
    float mn0 = 3.0e38f, mn1 = 3.0e38f, mn2 = 3.0e38f, mn3 = 3.0e38f;
#pragma unroll
    for (int kk = 0; kk < KK; ++kk) {
      int q = nb[pi][kk];
      float4 y4 = *(const float4*)&z[((size_t)(b * NN + q)) * ZW + co];
      float h0 = u4.x + y4.x, h1 = u4.y + y4.y, h2 = u4.z + y4.z, h3 = u4.w + y4.w;
      mx0 = fmaxf(mx0, h0); mn0 = fminf(mn0, h0);
      mx1 = fmaxf(mx1, h1); mn1 = fminf(mn1, h1);
      mx2 = fmaxf(mx2, h2); mn2 = fminf(mn2, h2);
      mx3 = fmaxf(mx3, h3); mn3 = fminf(mn3, h3);
      s0 += (double)h0; q0 += (double)h0 * (double)h0;
      s1 += (double)h1; q1 += (double)h1 * (double)h1;
      s2 += (double)h2; q2 += (double)h2 * (double)h2;
      s3 += (double)h3; q3 += (double)h3 * (double)h3;
    }
    *(float4*)&hmax[(size_t)p * O + co] = float4{mx0, mx1, mx2, mx3};
    *(float4*)&hmin[(size_t)p * O + co] = float4{mn0, mn1, mn2, mn3};
  }
  SS[0][t][0] = s0; SS[0][t][1] = s1; SS[0][t][2] = s2; SS[0][t][3] = s3;
  SS[1][t][0] = q0; SS[1][t][1] = q1; SS[1][t][2] = q2; SS[1][t][3] = q3;
  __syncthreads();
  if (slot == 0) {
    double a0 = 0.0, a1 = 0.0, a2 = 0.0, a3 = 0.0;
    double b0 = 0.0, b1 = 0.0, b2 = 0.0, b3 = 0.0;
#pragma unroll
    for (int sl = 0; sl < PTS; ++sl) {
      int tt = sl * TPP + lc;
      a0 += SS[0][tt][0]; a1 += SS[0][tt][1]; a2 += SS[0][tt][2]; a3 += SS[0][tt][3];
      b0 += SS[1][tt][0]; b1 += SS[1][tt][1]; b2 += SS[1][tt][2]; b3 += SS[1][tt][3];
    }
    double* pp = partials + (size_t)bid * (2 * O);
    pp[co + 0] = a0; pp[co + 1] = a1; pp[co + 2] = a2; pp[co + 3] = a3;
    pp[O + co + 0] = b0; pp[O + co + 1] = b1; pp[O + co + 2] = b2; pp[O + co + 3] = b3;
  }
}

// ============ reduce per-block partials -> sums ============
__global__ __launch_bounds__(256) void redsums_k(const double* __restrict__ P, int nblk,
                                                 int twoO, double* __restrict__ sums) {
  int j = blockIdx.x;
  int t = threadIdx.x;
  double s = 0.0;
  for (int b = t; b < nblk; b += 256) s += P[(size_t)b * twoO + j];
  __shared__ double L[256];
  L[t] = s; __syncthreads();
  for (int st = 128; st > 0; st >>= 1) {
    if (t < st) L[t] += L[t + st];
    __syncthreads();
  }
  if (t == 0) {
    int O = twoO >> 1;
    sums[j < O ? j : 1024 + (j - O)] = L[0];
  }
}

// ============ BN scale/shift from fp64 sums ============
__global__ __launch_bounds__(256) void mkscale_k(const double* __restrict__ sums,
                                                 const float* __restrict__ gam,
                                                 const float* __restrict__ bet,
                                                 int O, double invM,
                                                 float* __restrict__ scale,
                                                 float* __restrict__ shift) {
  int o = blockIdx.x * 256 + threadIdx.x;
  if (o >= O) return;
  double mean = sums[o] * invM;
  double var = sums[1024 + o] * invM - mean * mean;
  if (var < 0.0) var = 0.0;
  double r = 1.0 / sqrt(var + 1e-5);
  double s = (double)gam[o] * r;
  scale[o] = (float)s;
  shift[o] = (float)((double)bet[o] - mean * s);
}

// ============ apply BN + LeakyReLU via max/min; emits fp32 + bf16 hi + bf16 lo ============
__global__ __launch_bounds__(256) void apply_k(const float* __restrict__ hmax,
                                               const float* __restrict__ hmin,
                                               const float* __restrict__ scale,
                                               const float* __restrict__ shift,
                                               float* __restrict__ outb,
                                               __hip_bfloat16* __restrict__ outhi,
                                               __hip_bfloat16* __restrict__ outlo,
                                               int O, int ostride) {
  int gid = blockIdx.x * 256 + threadIdx.x;
  if (gid >= BB * NN * O) return;
  int p = gid / O, o = gid % O;
  float sc = scale[o];
  float v = (sc >= 0.f ? hmax[gid] : hmin[gid]) * sc + shift[o];
  float r = v >= 0.f ? v : 0.2f * v;
  __hip_bfloat16 hi = __float2bfloat16(r);
  float lo = r - __bfloat162float(hi);
  outb[(size_t)p * ostride + o] = r;
  outhi[(size_t)p * ostride + o] = hi;
  outlo[(size_t)p * ostride + o] = __float2bfloat16(lo);
}

// ============ final output ============
__global__ __launch_bounds__(256) void c5out_k(const float* __restrict__ mx5,
                                               const float* __restrict__ mn5,
                                               const float* __restrict__ scale,
                                               const float* __restrict__ shift,
                                               float* __restrict__ out) {
  int i = blockIdx.x * 256 + threadIdx.x;
  if (i >= BB * 1024) return;
  int o = i % 1024;
  float sc = scale[o];
  float v = (sc >= 0.f ? mx5[i] : mn5[i]) * sc + shift[o];
  out[i] = v >= 0.f ? v : 0.2f * v;
}

extern "C" void kernel_launch(void* const* d_in, const int* in_sizes, int n_in,
                              void* d_out, int out_size, void* d_ws, size_t ws_size,
                              hipStream_t stream) {
  const float* x  = (const float*)d_in[0];
  const float* W1 = (const float*)d_in[1];
  const float* g1 = (const float*)d_in[2];
  const float* b1 = (const float*)d_in[3];
  const float* W2 = (const float*)d_in[4];
  const float* g2 = (const float*)d_in[5];
  const float* b2 = (const float*)d_in[6];
  const float* W3 = (const float*)d_in[7];
  const float* g3 = (const float*)d_in[8];
  const float* b3 = (const float*)d_in[9];
  const float* W4 = (const float*)d_in[10];
  const float* g4 = (const float*)d_in[11];
  const float* b4 = (const float*)d_in[12];
  const float* W5 = (const float*)d_in[13];
  const float* g5 = (const float*)d_in[14];
  const float* b5 = (const float*)d_in[15];
  float* out = (float*)d_out;

  char* base = (char*)d_ws;
  size_t off = 0;
  auto alloc = [&](size_t nbytes) -> void* {
    void* p = (void*)(base + off);
    off += (nbytes + 255) & ~(size_t)255;
    return p;
  };
  float*  xxf   = (float*)alloc((size_t)BB * NN * 4);
  int*    idx   = (int*)alloc((size_t)BB * NN * KK * 4);
  int*    cand  = (int*)alloc((size_t)BB * NN * KSEL * 4);
  float*  scale = (float*)alloc(1024 * 4);
  float*  shift = (float*)alloc(1024 * 4);
  double* sums  = (double*)alloc(2048 * 8);
  float*  mx5   = (float*)alloc(8192 * 4);
  float*  mn5   = (float*)alloc(8192 * 4);
  float*  pmx   = (float*)alloc((size_t)128 * 1024 * 4);
  float*  pmn   = (float*)alloc((size_t)128 * 1024 * 4);
  double* psum  = (double*)alloc((size_t)128 * 1024 * 8);
  double* psq   = (double*)alloc((size_t)128 * 1024 * 8);
  float*  wmod  = (float*)alloc((size_t)512 * 128 * 4);
  __hip_bfloat16* wmodh = (__hip_bfloat16*)alloc((size_t)512 * 128 * 2);
  __hip_bfloat16* wmodl = (__hip_bfloat16*)alloc((size_t)512 * 128 * 2);
  __hip_bfloat16* w5b = (__hip_bfloat16*)alloc((size_t)1024 * 512 * 2);
  double* parts = (double*)alloc((size_t)1024 * 512 * 8);
  float*  xcat  = (float*)alloc((size_t)BB * NN * 512 * 4);
  __hip_bfloat16* xcatb  = (__hip_bfloat16*)alloc((size_t)BB * NN * 512 * 2);
  __hip_bfloat16* xcatlo = (__hip_bfloat16*)alloc((size_t)BB * NN * 512 * 2);
  float*  hmax  = (float*)alloc((size_t)BB * NN * 256 * 4);
  float*  hmin  = (float*)alloc((size_t)BB * NN * 256 * 4);
  size_t zoff = off;
  float*  zar   = (float*)alloc((size_t)BB * NN * 1024 * 4);  // z arena
  float*  dist  = (float*)zar;   // fp32 dist aliases zar (pd/topk finish before z written)
  size_t avail = (ws_size > zoff) ? (ws_size - zoff) : ((size_t)BB * NN * 1024 * 4);
  int CB = (int)(avail / ((size_t)NN * NN * 4));
  if (CB > BB) CB = BB;
  if (CB < 1) CB = 1;

  const int PPB = 16;
  const int NBLK = BB * NN / PPB;  // 1024

  auto run_layer = [&](const float* xin, const __hip_bfloat16* xinh,
                       const __hip_bfloat16* xinl, int stride, int Cin, int O,
                       const float* W, const float* gg, const float* bbeta,
                       int ooff, int variant) {
    // ---- kNN: select top-32 candidates + fp64 refine (top-20 exact) ----
    if (Cin == 3) {
      knn3_k<<<BB * NN / 16, 256, 0, stream>>>(xin, cand);
    } else {
      norms_k<<<64, 256, 0, stream>>>(xin, Cin, stride, xxf);
      for (int b0 = 0; b0 < BB; b0 += CB) {
        int cb = BB - b0; if (cb > CB) cb = CB;
        dim3 gpd(16, 16, cb);
        pdmfma_k<<<gpd, 512, 0, stream>>>(
            (const unsigned short*)xinh + (size_t)b0 * NN * stride,
            (const unsigned short*)xinl + (size_t)b0 * NN * stride,
            stride, (long long)NN * stride,
            dist, xxf + (size_t)b0 * NN, Cin);
        topk32_k<<<cb * 512, 256, 0, stream>>>(dist, b0 * NN, cand);
      }
    }
    if (Cin == 3)
      refine4_k<3><<<BB * NN / 4, 256, 0, stream>>>(xin, stride, cand, idx);
    else if (Cin == 64)
      refine4_k<64><<<BB * NN / 4, 256, 0, stream>>>(xin, stride, cand, idx);
    else
      refine4_k<128><<<BB * NN / 4, 256, 0, stream>>>(xin, stride, cand, idx);
    // ---- point-level GEMM: z = xin * [W_L ; W_R - W_L]^T ----
    wmod_k<<<(O * Cin + 255) / 256, 256, 0, stream>>>(W, O, Cin, wmod, wmodh, wmodl);
    if (Cin == 3) {
      dim3 gf(128, (2 * O) / 128, 1);
      gemm128_k<<<gf, 256, 0, stream>>>(xin, stride, wmod, Cin, zar, 2 * O, Cin);
    } else {
      dim3 gf(128, (2 * O) / 128, 1);
      gemm_fb_k<<<gf, 512, 0, stream>>>(
          (const unsigned short*)xinh, (const unsigned short*)xinl, stride,
          (const unsigned short*)wmodh, (const unsigned short*)wmodl, Cin,
          zar, 2 * O, Cin);
    }
    // ---- gather-reduce epilogue ----
    if (variant == 0)
      edgeep3_k<64, PPB><<<NBLK, 256, 0, stream>>>(zar, idx, hmax, hmin, parts);
    else if (variant == 1)
      edgeep3_k<128, PPB><<<NBLK, 256, 0, stream>>>(zar, idx, hmax, hmin, parts);
    else
      edgeep3_k<256, PPB><<<NBLK, 256, 0, stream>>>(zar, idx, hmax, hmin, parts);
    redsums_k<<<2 * O, 256, 0, stream>>>(parts, NBLK, 2 * O, sums);
    mkscale_k<<<(O + 255) / 256, 256, 0, stream>>>(
        sums, gg, bbeta, O, 1.0 / ((double)BB * NN * KK), scale, shift);
    apply_k<<<(BB * NN * O + 255) / 256, 256, 0, stream>>>(
        hmax, hmin, scale, shift, xcat + ooff, xcatb + ooff, xcatlo + ooff, O, 512);
  };

  run_layer(x,          nullptr,      nullptr,       3,   3,   64,  W1, g1, b1, 0,   0);
  run_layer(xcat + 0,   xcatb + 0,    xcatlo + 0,    512, 64,  64,  W2, g2, b2, 64,  0);
  run_layer(xcat + 64,  xcatb + 64,   xcatlo + 64,   512, 64,  128, W3, g3, b3, 128, 1);
  run_layer(xcat + 128, xcatb + 128,  xcatlo + 128,  512, 128, 256, W4, g4, b4, 256, 2);

  // conv5 via bf16 MFMA with fused stats (no h materialization)
  tobf16_k<<<(1024 * 512 + 255) / 256, 256, 0, stream>>>(W5, 1024 * 512, w5b);
  dim3 g5d(128, 8, 1);
  gemm_c5_k<<<g5d, 256, 0, stream>>>((const unsigned short*)xcatb, 512,
                                     (const unsigned short*)w5b, 512,
                                     pmx, pmn, psum, psq, 512);
  hipMemsetAsync(sums, 0, 2048 * 8, stream);
  c5red_k<<<32, 256, 0, stream>>>(pmx, pmn, psum, psq, mx5, mn5, sums);
  mkscale_k<<<4, 256, 0, stream>>>(sums, g5, b5, 1024, 1.0 / ((double)BB * NN),
                                   scale, shift);
  c5out_k<<<32, 256, 0, stream>>>(mx5, mn5, scale, shift, out);
}